// Round 18
// baseline (84.541 us; speedup 1.0000x reference)
//
#include <hip/hip_runtime.h>
#include <stdint.h>

typedef __attribute__((ext_vector_type(8))) short short8;      // 8 x bf16 (MFMA A/B frag)
typedef __attribute__((ext_vector_type(4))) float f32x4;       // MFMA acc frag
typedef __attribute__((ext_vector_type(4))) float f4;
typedef __attribute__((ext_vector_type(4))) unsigned short us4;
typedef __attribute__((ext_vector_type(4))) unsigned int u32x4;

typedef unsigned short ushort_t;

__device__ __forceinline__ ushort_t f2bf(float f) {
    union { float f; uint32_t u; } c; c.f = f;
    uint32_t u = c.u;
    uint32_t r = u + 0x7fffu + ((u >> 16) & 1u);   // RNE
    return (ushort_t)(r >> 16);
}
__device__ __forceinline__ float bf2f(ushort_t h) {
    union { uint32_t u; float f; } c; c.u = ((uint32_t)h) << 16;
    return c.f;
}
// HW packed f32->bf16 (RNE), 2 elems per VALU op
__device__ __forceinline__ uint32_t cvtpk(float lo, float hi) {
    uint32_t r;
    asm("v_cvt_pk_bf16_f32 %0, %1, %2" : "=v"(r) : "v"(lo), "v"(hi));
    return r;
}

// async global->LDS, 16B per lane; LDS dest = wave-uniform base + lane*16
typedef const __attribute__((address_space(1))) unsigned int as1_uint;
typedef __attribute__((address_space(3))) unsigned int as3_uint;
__device__ __forceinline__ void gload_lds16(const void* g, void* l) {
    __builtin_amdgcn_global_load_lds((as1_uint*)g, (as3_uint*)l, 16, 0, 0);
}

// LDS tile [R rows][64 cols] bf16, XOR-swizzled: element (r,c) lives at
// ushort index r*64 + (c ^ ((r&7)<<3)). LDS stays linear for global_load_lds;
// the inverse permutation is applied on the GLOBAL source chunk (rule #21).
#define SWIDX(r, c) ((r) * 64 + ((c) ^ (((r) & 7) << 3)))

// ---------------------------------------------------------------------------
// Weight prep (small weights): W1t hi/lo ([128][1024]) and Ct ([1024][64]).
// ---------------------------------------------------------------------------
__global__ void prep_weights(const float* __restrict__ gate_W, const float* __restrict__ B_W,
                             const float* __restrict__ C_W,
                             ushort_t* __restrict__ W1t_hi, ushort_t* __restrict__ W1t_lo,
                             ushort_t* __restrict__ Ct)
{
    int idx = blockIdx.x * 256 + threadIdx.x;
    int stride = gridDim.x * 256;
    for (int i = idx; i < 128 * 1024; i += stride) {
        int nn = i >> 10, kk = i & 1023;
        float v = (nn < 64) ? gate_W[kk * 64 + nn] : B_W[kk * 64 + (nn - 64)];
        ushort_t h = f2bf(v);
        W1t_hi[i] = h;
        W1t_lo[i] = f2bf(v - bf2f(h));
    }
    for (int i = idx; i < 1024 * 64; i += stride) {
        int nn = i >> 6, kk = i & 63;
        Ct[i] = f2bf(C_W[kk * 1024 + nn]);
    }
}

// ---------------------------------------------------------------------------
// outWt transpose via LDS 64x64 tile: coalesced read (along nn) AND coalesced
// write (along kk). The old strided read dragged a 64B line per 4B element.
// (Correctness-verified in R16's run; isolated here onto the R14 base.)
// ---------------------------------------------------------------------------
__global__ __launch_bounds__(256)
void prep_outwt(const float* __restrict__ out_W, ushort_t* __restrict__ outWt)
{
    __shared__ ushort_t T[64][65];   // +1 pad
    const int kk0 = blockIdx.x * 64, nn0 = blockIdx.y * 64;
    const int tid = threadIdx.x;
#pragma unroll
    for (int p = 0; p < 16; ++p) {
        int r = p * 4 + (tid >> 6);      // kk local
        int c = tid & 63;                // nn local (coalesced)
        T[c][r] = f2bf(out_W[(size_t)(kk0 + r) * 1024 + nn0 + c]);
    }
    __syncthreads();
#pragma unroll
    for (int p = 0; p < 2; ++p) {
        int idx = tid + p * 256;         // 512 chunks of 8
        int r = idx >> 3;                // nn local
        int cc = (idx & 7) * 8;          // kk local
        short8 v;
#pragma unroll
        for (int j = 0; j < 8; ++j) v[j] = (short)T[r][cc + j];
        *(short8*)(outWt + (size_t)(nn0 + r) * 1024 + kk0 + cc) = v;
    }
}

// ---------------------------------------------------------------------------
// P1: Z^T[n][s] = sum_k W1[k][n] * x[s][k], 2-PASS split precision.
// Split-K (2 chunks of 512). Writes x_hi (bf16 of x) as a staging byproduct.
// x conversion via HW v_cvt_pk_bf16_f32 and 16B stores.
// ---------------------------------------------------------------------------
__global__ __launch_bounds__(256, 2)
void p1_kernel(const float* __restrict__ x,
               const ushort_t* __restrict__ W1t_hi, const ushort_t* __restrict__ W1t_lo,
               ushort_t* __restrict__ x_hi, float* __restrict__ Zpart)
{
    __shared__ ushort_t Ash[128 * 64];
    __shared__ ushort_t Asl[128 * 64];
    __shared__ ushort_t Bsh[64 * 64];

    const int tid = threadIdx.x;
    const int wave = tid >> 6, lane = tid & 63;
    const int wm = wave >> 1, wn = wave & 1;
    const int s0 = blockIdx.x * 64;
    const int kc = blockIdx.y;

    f32x4 acc[4][2];
#pragma unroll
    for (int i = 0; i < 4; i++)
#pragma unroll
        for (int j = 0; j < 2; j++) { f32x4 z = {0.f,0.f,0.f,0.f}; acc[i][j] = z; }

    for (int kt = 0; kt < 8; ++kt) {
        const int k0 = kc * 512 + kt * 64;
#pragma unroll
        for (int p = 0; p < 4; ++p) {
            int c = p * 256 + wave * 64 + lane;
            int row = c >> 3, col = (c & 7) * 8;
            gload_lds16(W1t_hi + (size_t)row * 1024 + k0 + col,
                        &Ash[(p * 256 + wave * 64) * 8]);
            gload_lds16(W1t_lo + (size_t)row * 1024 + k0 + col,
                        &Asl[(p * 256 + wave * 64) * 8]);
        }
        // x -> bf16 staging: 512 chunks of 8 floats; 2 per thread
#pragma unroll
        for (int p = 0; p < 2; ++p) {
            int f = tid + p * 256;
            int row = f >> 3, col = (f & 7) * 8;
            const float* src = x + (size_t)(s0 + row) * 1024 + k0 + col;
            f4 v0 = *(const f4*)src;
            f4 v1 = *(const f4*)(src + 4);
            u32x4 pk = { cvtpk(v0[0], v0[1]), cvtpk(v0[2], v0[3]),
                         cvtpk(v1[0], v1[1]), cvtpk(v1[2], v1[3]) };
            *(u32x4*)&Bsh[row * 64 + col] = pk;
            *(u32x4*)(x_hi + (size_t)(s0 + row) * 1024 + k0 + col) = pk;
        }
        __syncthreads();
#pragma unroll
        for (int kk = 0; kk < 2; ++kk) {
            const int kb = kk * 32 + (lane >> 4) * 8;
            short8 ah[4], al[4], bh[2];
#pragma unroll
            for (int fm = 0; fm < 4; fm++) {
                int r = wm * 64 + fm * 16 + (lane & 15);
                ah[fm] = *(const short8*)&Ash[r * 64 + kb];
                al[fm] = *(const short8*)&Asl[r * 64 + kb];
            }
#pragma unroll
            for (int fn = 0; fn < 2; fn++) {
                int r = wn * 32 + fn * 16 + (lane & 15);
                bh[fn] = *(const short8*)&Bsh[r * 64 + kb];
            }
#pragma unroll
            for (int fm = 0; fm < 4; fm++)
#pragma unroll
                for (int fn = 0; fn < 2; fn++) {
                    acc[fm][fn] = __builtin_amdgcn_mfma_f32_16x16x32_bf16(ah[fm], bh[fn], acc[fm][fn], 0, 0, 0);
                    acc[fm][fn] = __builtin_amdgcn_mfma_f32_16x16x32_bf16(al[fm], bh[fn], acc[fm][fn], 0, 0, 0);
                }
        }
        __syncthreads();
    }
#pragma unroll
    for (int fm = 0; fm < 4; fm++) {
#pragma unroll
        for (int fn = 0; fn < 2; fn++) {
            int scol = s0 + wn * 32 + fn * 16 + (lane & 15);
            int b = scol >> 12, sb = scol & 4095;
            int nbase = wm * 64 + fm * 16 + ((lane >> 4) << 2);
#pragma unroll
            for (int r = 0; r < 4; r++) {
                Zpart[((size_t)kc * 512 + b * 128 + nbase + r) * 4096 + sb] = acc[fm][fn][r];
            }
        }
    }
}

// ---------------------------------------------------------------------------
// Scan: combine split-K partials, gate = sigmoid(zg+bias), h_t = a_t*h + b_t.
// Output hT[b*64+n][s] bf16 (packed via cvt_pk, 16B stores).
// ---------------------------------------------------------------------------
__global__ __launch_bounds__(256)
void scan_kernel(const float* __restrict__ Zpart, const float* __restrict__ gate_b,
                 ushort_t* __restrict__ hT)
{
    __shared__ float SA[256], SB[256];
    const int bn = blockIdx.x;
    const int t = threadIdx.x;
    const int b = bn >> 6, n = bn & 63;
    const float gb = gate_b[n];
    const float* g0 = Zpart + ((size_t)(b * 128 + n)) * 4096;
    const float* g1 = g0 + (size_t)512 * 4096;
    const float* b0 = Zpart + ((size_t)(b * 128 + 64 + n)) * 4096;
    const float* b1 = b0 + (size_t)512 * 4096;
    const int sb = t * 16;

    float a[16], bb[16];
#pragma unroll
    for (int q = 0; q < 4; q++) {
        f4 vg0 = *(const f4*)(g0 + sb + q * 4);
        f4 vg1 = *(const f4*)(g1 + sb + q * 4);
        f4 vb0 = *(const f4*)(b0 + sb + q * 4);
        f4 vb1 = *(const f4*)(b1 + sb + q * 4);
#pragma unroll
        for (int j = 0; j < 4; j++) {
            a[q * 4 + j] = 1.f / (1.f + __expf(-(vg0[j] + vg1[j] + gb)));
            bb[q * 4 + j] = vb0[j] + vb1[j];
        }
    }
    float A = 1.f, Bv = 0.f;
#pragma unroll
    for (int i = 0; i < 16; i++) { Bv = a[i] * Bv + bb[i]; A *= a[i]; }
    SA[t] = A; SB[t] = Bv;
    __syncthreads();
    for (int off = 1; off < 256; off <<= 1) {
        float a1 = 1.f, b1v = 0.f;
        if (t >= off) { a1 = SA[t - off]; b1v = SB[t - off]; }
        float a2 = SA[t], b2 = SB[t];
        __syncthreads();
        SA[t] = a1 * a2;
        SB[t] = a2 * b1v + b2;
        __syncthreads();
    }
    float h = (t == 0) ? 0.f : SB[t - 1];
    float hv[16];
#pragma unroll
    for (int i = 0; i < 16; i++) {
        h = a[i] * h + bb[i];
        hv[i] = h;
    }
    ushort_t* dst = hT + (size_t)bn * 4096 + sb;
    u32x4 o0 = { cvtpk(hv[0], hv[1]),  cvtpk(hv[2], hv[3]),
                 cvtpk(hv[4], hv[5]),  cvtpk(hv[6], hv[7]) };
    u32x4 o1 = { cvtpk(hv[8], hv[9]),  cvtpk(hv[10], hv[11]),
                 cvtpk(hv[12], hv[13]), cvtpk(hv[14], hv[15]) };
    *(u32x4*)(dst)     = o0;
    *(u32x4*)(dst + 8) = o1;
}

// ---------------------------------------------------------------------------
// gemm_out256: out = (h@C_W) * sigmoid(x_hi @ outWt^T).
// FROZEN R11 (best known, ~56 us): 256x256 tile, 8 waves (2Mx4N), dbuf LDS,
// T2 XOR-swizzle, counted schedule with cross-phase A-quarter register
// prefetch (aR0/aR1, lgkmcnt(4)), vmcnt(2)@q0 / vmcnt(2)@q2, stages only into
// buf^1, conflict-free hT transpose (0 bank conflicts measured), XCD chunk map.
// ---------------------------------------------------------------------------
__global__ __launch_bounds__(512, 2)
void gemm_out256(const ushort_t* __restrict__ x_hi, const ushort_t* __restrict__ outWt,
                 const ushort_t* __restrict__ hT, const ushort_t* __restrict__ Ct,
                 float* __restrict__ out)
{
    __shared__ ushort_t As[2][256 * 64];   // 64 KiB
    __shared__ ushort_t Bs[2][256 * 64];   // 64 KiB

    const int tid = threadIdx.x;
    const int wave = tid >> 6, lane = tid & 63;
    const int wm = wave >> 2;          // 0..1
    const int wn = wave & 3;           // 0..3

    // XCD chunking: XCD k (= flat&7) owns m-tiles 8k..8k+7, sweeps n within.
    const int flat = blockIdx.x;
    const int swz = (flat & 7) * 32 + (flat >> 3);
    const int m0 = (swz >> 2) * 256;
    const int n0 = (swz & 3) * 256;

    const int lcol0 = (lane >> 4) * 8;
    const int lrow = lane & 15;
    const int lxor = (lrow & 7) << 3;

    // per-lane LDS read offsets (elements); quarter = +q*4096
    const int aOff0 = (wm * 32 + lrow) * 64 + (lcol0 ^ lxor);
    const int aOff1 = (wm * 32 + lrow) * 64 + ((32 + lcol0) ^ lxor);
    const int bOff0 = (wn * 64 + lrow) * 64 + (lcol0 ^ lxor);
    const int bOff1 = (wn * 64 + lrow) * 64 + ((32 + lcol0) ^ lxor);

    // persistent global stage streams (advance +64 elements per stage)
    const int rl0 = tid >> 3;                       // 0..63
    const int col0 = ((tid & 7) ^ (rl0 & 7)) << 3;  // inverse-swizzled source
    const ushort_t* gB0a = outWt + (size_t)(n0 + rl0) * 1024 + col0;
    const ushort_t* gB0b = gB0a + 64 * 1024;
    const ushort_t* gB1a = outWt + (size_t)(n0 + 128 + rl0) * 1024 + col0;
    const ushort_t* gB1b = gB1a + 64 * 1024;
    const ushort_t* gA0a = x_hi + (size_t)(m0 + rl0) * 1024 + col0;
    const ushort_t* gA0b = gA0a + 64 * 1024;
    const ushort_t* gA1a = x_hi + (size_t)(m0 + 128 + rl0) * 1024 + col0;
    const ushort_t* gA1b = gA1a + 64 * 1024;

    auto STG = [&](const ushort_t*& ga, const ushort_t*& gb, ushort_t* ldsbase) {
        gload_lds16(ga, ldsbase + wave * 512);
        gload_lds16(gb, ldsbase + 4096 + wave * 512);
        ga += 64; gb += 64;
    };

    f32x4 acc[8][4];
#pragma unroll
    for (int i = 0; i < 8; i++)
#pragma unroll
        for (int j = 0; j < 4; j++) { f32x4 z = {0.f,0.f,0.f,0.f}; acc[i][j] = z; }

    // prologue: stage tile 0; retire B0,B1,A0 (A1 stays in flight); read quarter0.
    STG(gB0a, gB0b, &Bs[0][0]);
    STG(gB1a, gB1b, &Bs[0][8192]);
    STG(gA0a, gA0b, &As[0][0]);
    STG(gA1a, gA1b, &As[0][8192]);
    asm volatile("s_waitcnt vmcnt(2)" ::: "memory");
    __builtin_amdgcn_s_barrier();

    short8 aR0[2][2], aR1[2][2], bfr[4][2];
#pragma unroll
    for (int mm = 0; mm < 2; ++mm) {
        aR0[mm][0] = *(const short8*)&As[0][aOff0 + mm * 1024];
        aR0[mm][1] = *(const short8*)&As[0][aOff1 + mm * 1024];
    }

#define MFMA_Q(q, AR)                                                              \
    do {                                                                           \
        __builtin_amdgcn_s_setprio(1);                                             \
        _Pragma("unroll") for (int mm = 0; mm < 2; ++mm)                           \
            _Pragma("unroll") for (int fn = 0; fn < 4; ++fn) {                     \
                acc[2*(q)+mm][fn] = __builtin_amdgcn_mfma_f32_16x16x32_bf16(       \
                    AR[mm][0], bfr[fn][0], acc[2*(q)+mm][fn], 0, 0, 0);            \
                acc[2*(q)+mm][fn] = __builtin_amdgcn_mfma_f32_16x16x32_bf16(       \
                    AR[mm][1], bfr[fn][1], acc[2*(q)+mm][fn], 0, 0, 0);            \
            }                                                                      \
        __builtin_amdgcn_s_setprio(0);                                             \
    } while (0)

    for (int t = 0; t < 16; ++t) {
        const int bc = t & 1;
        const ushort_t* as = &As[bc][0];
        const ushort_t* bs = &Bs[bc][0];
        const ushort_t* asn = &As[bc ^ 1][0];

        // ---- q0: MFMA quarter0 (aR0); read B(t) + quarter1 -> aR1 ----
        if (t < 15) STG(gB0a, gB0b, &Bs[bc ^ 1][0]);           // B0(t+1)
#pragma unroll
        for (int fn = 0; fn < 4; ++fn) {
            bfr[fn][0] = *(const short8*)(bs + bOff0 + fn * 1024);
            bfr[fn][1] = *(const short8*)(bs + bOff1 + fn * 1024);
        }
#pragma unroll
        for (int mm = 0; mm < 2; ++mm) {
            aR1[mm][0] = *(const short8*)(as + aOff0 + 4096 + mm * 1024);
            aR1[mm][1] = *(const short8*)(as + aOff1 + 4096 + mm * 1024);
        }
        asm volatile("s_waitcnt lgkmcnt(4)" ::: "memory");
        __builtin_amdgcn_sched_barrier(0);
        MFMA_Q(0, aR0);
        if (t < 15) { asm volatile("s_waitcnt vmcnt(2)" ::: "memory"); }  // retire A1(t)
        else        { asm volatile("s_waitcnt vmcnt(0)" ::: "memory"); }
        __builtin_amdgcn_s_barrier();

        // ---- q1: MFMA quarter1 (aR1); read quarter2 -> aR0 ----
        if (t < 15) {
            STG(gB1a, gB1b, &Bs[bc ^ 1][8192]);                // B1(t+1)
            STG(gA0a, gA0b, &As[bc ^ 1][0]);                   // A0(t+1)
        }
#pragma unroll
        for (int mm = 0; mm < 2; ++mm) {
            aR0[mm][0] = *(const short8*)(as + aOff0 + 2 * 4096 + mm * 1024);
            aR0[mm][1] = *(const short8*)(as + aOff1 + 2 * 4096 + mm * 1024);
        }
        asm volatile("s_waitcnt lgkmcnt(4)" ::: "memory");
        __builtin_amdgcn_sched_barrier(0);
        MFMA_Q(1, aR1);
        __builtin_amdgcn_s_barrier();

        // ---- q2: MFMA quarter2 (aR0); read quarter3 -> aR1 ----
        if (t < 15) STG(gA1a, gA1b, &As[bc ^ 1][8192]);        // A1(t+1)
#pragma unroll
        for (int mm = 0; mm < 2; ++mm) {
            aR1[mm][0] = *(const short8*)(as + aOff0 + 3 * 4096 + mm * 1024);
            aR1[mm][1] = *(const short8*)(as + aOff1 + 3 * 4096 + mm * 1024);
        }
        asm volatile("s_waitcnt lgkmcnt(4)" ::: "memory");
        __builtin_amdgcn_sched_barrier(0);
        MFMA_Q(2, aR0);
        if (t < 15) { asm volatile("s_waitcnt vmcnt(2)" ::: "memory"); }  // retire B0,B1,A0(t+1)
        __builtin_amdgcn_s_barrier();

        // ---- q3: MFMA quarter3 (aR1); read quarter0(t+1) -> aR0 ----
        if (t < 15) {
#pragma unroll
            for (int mm = 0; mm < 2; ++mm) {
                aR0[mm][0] = *(const short8*)(asn + aOff0 + mm * 1024);
                aR0[mm][1] = *(const short8*)(asn + aOff1 + mm * 1024);
            }
            asm volatile("s_waitcnt lgkmcnt(4)" ::: "memory");
        } else {
            asm volatile("s_waitcnt lgkmcnt(0)" ::: "memory");
        }
        __builtin_amdgcn_sched_barrier(0);
        MFMA_Q(3, aR1);
        __builtin_amdgcn_s_barrier();
    }
#undef MFMA_Q

    // ---------- fused y epilogue: y = h @ C_W on this tile (K = 64) ----------
    const int b64 = (m0 >> 12) * 64;
    const int sb0 = m0 & 4095;
    // Bs[0] <- Ct rows n0..n0+255 (gload_lds, pre-swizzled source)
#pragma unroll
    for (int p = 0; p < 4; ++p) {
        int c = p * 512 + wave * 64 + lane;
        int row = c >> 3;
        int col = (((c & 7) ^ (row & 7)) << 3);
        gload_lds16(Ct + (size_t)(n0 + row) * 64 + col,
                    &Bs[0][(p * 512 + wave * 64) * 8]);
    }
    // As[0] <- transpose(hT). Conflict-free: kn = c&63 per-lane consecutive,
    // mc = c>>6 wave-uniform -> 64 lanes write one row, 2 lanes/bank = free.
#pragma unroll
    for (int p = 0; p < 4; ++p) {
        int c = tid + p * 512;           // kn = c&63, mc = c>>6 (0..31)
        int kn = c & 63, mc = c >> 6;
        short8 v = *(const short8*)(hT + (size_t)(b64 + kn) * 4096 + sb0 + mc * 8);
#pragma unroll
        for (int j = 0; j < 8; ++j)
            As[0][SWIDX(mc * 8 + j, kn)] = (ushort_t)v[j];
    }
    __syncthreads();

    short8 by[4][2];
#pragma unroll
    for (int fn = 0; fn < 4; fn++)
#pragma unroll
        for (int kk = 0; kk < 2; kk++) {
            int r = wn * 64 + fn * 16 + lrow;
            by[fn][kk] = *(const short8*)&Bs[0][SWIDX(r, kk * 32 + lcol0)];
        }

#pragma unroll
    for (int g = 0; g < 4; g++) {        // register-sliced: 2 m-frags at a time
        f32x4 ty[2][4];
#pragma unroll
        for (int mm = 0; mm < 2; mm++)
#pragma unroll
            for (int fn = 0; fn < 4; fn++) { f32x4 z = {0.f,0.f,0.f,0.f}; ty[mm][fn] = z; }
#pragma unroll
        for (int mm = 0; mm < 2; mm++) {
            int r = g * 64 + wm * 32 + mm * 16 + lrow;
            short8 a0 = *(const short8*)&As[0][SWIDX(r, lcol0)];
            short8 a1 = *(const short8*)&As[0][SWIDX(r, 32 + lcol0)];
#pragma unroll
            for (int fn = 0; fn < 4; fn++) {
                ty[mm][fn] = __builtin_amdgcn_mfma_f32_16x16x32_bf16(a0, by[fn][0], ty[mm][fn], 0, 0, 0);
                ty[mm][fn] = __builtin_amdgcn_mfma_f32_16x16x32_bf16(a1, by[fn][1], ty[mm][fn], 0, 0, 0);
            }
        }
#pragma unroll
        for (int mm = 0; mm < 2; mm++)
#pragma unroll
            for (int fn = 0; fn < 4; fn++) {
                int col = n0 + wn * 64 + fn * 16 + lrow;
                int rbase = m0 + g * 64 + wm * 32 + mm * 16 + ((lane >> 4) << 2);
#pragma unroll
                for (int r = 0; r < 4; r++) {
                    float og = 1.f / (1.f + __expf(-acc[g * 2 + mm][fn][r]));
                    out[(size_t)(rbase + r) * 1024 + col] = ty[mm][fn][r] * og;
                }
            }
    }
}

// ---------------------------------------------------------------------------
extern "C" void kernel_launch(void* const* d_in, const int* in_sizes, int n_in,
                              void* d_out, int out_size, void* d_ws, size_t ws_size,
                              hipStream_t stream)
{
    const float* x      = (const float*)d_in[0];   // (4,4096,1024)
    const float* gate_W = (const float*)d_in[1];   // (1024,64)
    const float* gate_b = (const float*)d_in[2];   // (64,)
    const float* B_W    = (const float*)d_in[3];   // (1024,64)
    const float* C_W    = (const float*)d_in[4];   // (64,1024)
    const float* out_W  = (const float*)d_in[5];   // (1024,1024)
    // d_in[6] mix_weight cancels (h_next == h_final); d_in[7] chunk_size unused.
    float* out = (float*)d_out;

    char* ws = (char*)d_ws;
    float*    Zpart  = (float*)(ws + 0);            // 16 MiB [2][512][4096] fp32
    ushort_t* hT     = (ushort_t*)(ws + 16777216);  //  2 MiB [256][4096]
    ushort_t* x_hi   = (ushort_t*)(ws + 18874368);  // 32 MiB [16384][1024]
    ushort_t* W1t_hi = (ushort_t*)(ws + 52428800);  // [128][1024]
    ushort_t* W1t_lo = (ushort_t*)(ws + 52690944);
    ushort_t* outWt  = (ushort_t*)(ws + 52953088);  // [1024][1024]
    ushort_t* Ct     = (ushort_t*)(ws + 55050240);  // [1024][64]

    prep_weights<<<64, 256, 0, stream>>>(gate_W, B_W, C_W, W1t_hi, W1t_lo, Ct);
    prep_outwt<<<dim3(16, 16), 256, 0, stream>>>(out_W, outWt);

    p1_kernel<<<dim3(256, 2), 256, 0, stream>>>(x, W1t_hi, W1t_lo, x_hi, Zpart);

    scan_kernel<<<256, 256, 0, stream>>>(Zpart, gate_b, hT);

    gemm_out256<<<256, 512, 0, stream>>>(x_hi, outWt, hT, Ct, out);
}

// Round 19
// 83.384 us; speedup vs baseline: 1.0139x; 1.0139x over previous
//
#include <hip/hip_runtime.h>
#include <stdint.h>

typedef __attribute__((ext_vector_type(8))) short short8;      // 8 x bf16 (MFMA A/B frag)
typedef __attribute__((ext_vector_type(4))) float f32x4;       // MFMA acc frag
typedef __attribute__((ext_vector_type(4))) float f4;
typedef __attribute__((ext_vector_type(4))) unsigned short us4;
typedef __attribute__((ext_vector_type(4))) unsigned int u32x4;

typedef unsigned short ushort_t;

__device__ __forceinline__ ushort_t f2bf(float f) {
    union { float f; uint32_t u; } c; c.f = f;
    uint32_t u = c.u;
    uint32_t r = u + 0x7fffu + ((u >> 16) & 1u);   // RNE
    return (ushort_t)(r >> 16);
}
__device__ __forceinline__ float bf2f(ushort_t h) {
    union { uint32_t u; float f; } c; c.u = ((uint32_t)h) << 16;
    return c.f;
}
// HW packed f32->bf16 (RNE), 2 elems per VALU op
__device__ __forceinline__ uint32_t cvtpk(float lo, float hi) {
    uint32_t r;
    asm("v_cvt_pk_bf16_f32 %0, %1, %2" : "=v"(r) : "v"(lo), "v"(hi));
    return r;
}

// async global->LDS, 16B per lane; LDS dest = wave-uniform base + lane*16
typedef const __attribute__((address_space(1))) unsigned int as1_uint;
typedef __attribute__((address_space(3))) unsigned int as3_uint;
__device__ __forceinline__ void gload_lds16(const void* g, void* l) {
    __builtin_amdgcn_global_load_lds((as1_uint*)g, (as3_uint*)l, 16, 0, 0);
}

// LDS tile [R rows][64 cols] bf16, XOR-swizzled: element (r,c) lives at
// ushort index r*64 + (c ^ ((r&7)<<3)). LDS stays linear for global_load_lds;
// the inverse permutation is applied on the GLOBAL source chunk (rule #21).
#define SWIDX(r, c) ((r) * 64 + ((c) ^ (((r) & 7) << 3)))

// ---------------------------------------------------------------------------
// Weight prep: B^T ([N][K]) layouts.
// ---------------------------------------------------------------------------
__global__ void prep_weights(const float* __restrict__ gate_W, const float* __restrict__ B_W,
                             const float* __restrict__ C_W, const float* __restrict__ out_W,
                             ushort_t* __restrict__ W1t_hi, ushort_t* __restrict__ W1t_lo,
                             ushort_t* __restrict__ outWt, ushort_t* __restrict__ Ct)
{
    int idx = blockIdx.x * 256 + threadIdx.x;
    int stride = gridDim.x * 256;
    for (int i = idx; i < 1024 * 1024; i += stride) {
        int nn = i >> 10, kk = i & 1023;
        outWt[i] = f2bf(out_W[kk * 1024 + nn]);
    }
    for (int i = idx; i < 128 * 1024; i += stride) {
        int nn = i >> 10, kk = i & 1023;
        float v = (nn < 64) ? gate_W[kk * 64 + nn] : B_W[kk * 64 + (nn - 64)];
        ushort_t h = f2bf(v);
        W1t_hi[i] = h;
        W1t_lo[i] = f2bf(v - bf2f(h));
    }
    for (int i = idx; i < 1024 * 64; i += stride) {
        int nn = i >> 6, kk = i & 63;
        Ct[i] = f2bf(C_W[kk * 1024 + nn]);
    }
}

// ---------------------------------------------------------------------------
// P1: Z^T[n][s] = sum_k W1[k][n] * x[s][k], 2-PASS split precision.
// Split-K (2 chunks of 512). Writes x_hi (bf16 of x) as a staging byproduct.
// x conversion via HW v_cvt_pk_bf16_f32 and 16B stores.
// ---------------------------------------------------------------------------
__global__ __launch_bounds__(256, 2)
void p1_kernel(const float* __restrict__ x,
               const ushort_t* __restrict__ W1t_hi, const ushort_t* __restrict__ W1t_lo,
               ushort_t* __restrict__ x_hi, float* __restrict__ Zpart)
{
    __shared__ ushort_t Ash[128 * 64];
    __shared__ ushort_t Asl[128 * 64];
    __shared__ ushort_t Bsh[64 * 64];

    const int tid = threadIdx.x;
    const int wave = tid >> 6, lane = tid & 63;
    const int wm = wave >> 1, wn = wave & 1;
    const int s0 = blockIdx.x * 64;
    const int kc = blockIdx.y;

    f32x4 acc[4][2];
#pragma unroll
    for (int i = 0; i < 4; i++)
#pragma unroll
        for (int j = 0; j < 2; j++) { f32x4 z = {0.f,0.f,0.f,0.f}; acc[i][j] = z; }

    for (int kt = 0; kt < 8; ++kt) {
        const int k0 = kc * 512 + kt * 64;
#pragma unroll
        for (int p = 0; p < 4; ++p) {
            int c = p * 256 + wave * 64 + lane;
            int row = c >> 3, col = (c & 7) * 8;
            gload_lds16(W1t_hi + (size_t)row * 1024 + k0 + col,
                        &Ash[(p * 256 + wave * 64) * 8]);
            gload_lds16(W1t_lo + (size_t)row * 1024 + k0 + col,
                        &Asl[(p * 256 + wave * 64) * 8]);
        }
        // x -> bf16 staging: 512 chunks of 8 floats; 2 per thread
#pragma unroll
        for (int p = 0; p < 2; ++p) {
            int f = tid + p * 256;
            int row = f >> 3, col = (f & 7) * 8;
            const float* src = x + (size_t)(s0 + row) * 1024 + k0 + col;
            f4 v0 = *(const f4*)src;
            f4 v1 = *(const f4*)(src + 4);
            u32x4 pk = { cvtpk(v0[0], v0[1]), cvtpk(v0[2], v0[3]),
                         cvtpk(v1[0], v1[1]), cvtpk(v1[2], v1[3]) };
            *(u32x4*)&Bsh[row * 64 + col] = pk;
            *(u32x4*)(x_hi + (size_t)(s0 + row) * 1024 + k0 + col) = pk;
        }
        __syncthreads();
#pragma unroll
        for (int kk = 0; kk < 2; ++kk) {
            const int kb = kk * 32 + (lane >> 4) * 8;
            short8 ah[4], al[4], bh[2];
#pragma unroll
            for (int fm = 0; fm < 4; fm++) {
                int r = wm * 64 + fm * 16 + (lane & 15);
                ah[fm] = *(const short8*)&Ash[r * 64 + kb];
                al[fm] = *(const short8*)&Asl[r * 64 + kb];
            }
#pragma unroll
            for (int fn = 0; fn < 2; fn++) {
                int r = wn * 32 + fn * 16 + (lane & 15);
                bh[fn] = *(const short8*)&Bsh[r * 64 + kb];
            }
#pragma unroll
            for (int fm = 0; fm < 4; fm++)
#pragma unroll
                for (int fn = 0; fn < 2; fn++) {
                    acc[fm][fn] = __builtin_amdgcn_mfma_f32_16x16x32_bf16(ah[fm], bh[fn], acc[fm][fn], 0, 0, 0);
                    acc[fm][fn] = __builtin_amdgcn_mfma_f32_16x16x32_bf16(al[fm], bh[fn], acc[fm][fn], 0, 0, 0);
                }
        }
        __syncthreads();
    }
#pragma unroll
    for (int fm = 0; fm < 4; fm++) {
#pragma unroll
        for (int fn = 0; fn < 2; fn++) {
            int scol = s0 + wn * 32 + fn * 16 + (lane & 15);
            int b = scol >> 12, sb = scol & 4095;
            int nbase = wm * 64 + fm * 16 + ((lane >> 4) << 2);
#pragma unroll
            for (int r = 0; r < 4; r++) {
                Zpart[((size_t)kc * 512 + b * 128 + nbase + r) * 4096 + sb] = acc[fm][fn][r];
            }
        }
    }
}

// ---------------------------------------------------------------------------
// Scan: combine split-K partials, gate = sigmoid(zg+bias), h_t = a_t*h + b_t.
// Output hT[b*64+n][s] bf16 (packed via cvt_pk, 16B stores).
// ---------------------------------------------------------------------------
__global__ __launch_bounds__(256)
void scan_kernel(const float* __restrict__ Zpart, const float* __restrict__ gate_b,
                 ushort_t* __restrict__ hT)
{
    __shared__ float SA[256], SB[256];
    const int bn = blockIdx.x;
    const int t = threadIdx.x;
    const int b = bn >> 6, n = bn & 63;
    const float gb = gate_b[n];
    const float* g0 = Zpart + ((size_t)(b * 128 + n)) * 4096;
    const float* g1 = g0 + (size_t)512 * 4096;
    const float* b0 = Zpart + ((size_t)(b * 128 + 64 + n)) * 4096;
    const float* b1 = b0 + (size_t)512 * 4096;
    const int sb = t * 16;

    float a[16], bb[16];
#pragma unroll
    for (int q = 0; q < 4; q++) {
        f4 vg0 = *(const f4*)(g0 + sb + q * 4);
        f4 vg1 = *(const f4*)(g1 + sb + q * 4);
        f4 vb0 = *(const f4*)(b0 + sb + q * 4);
        f4 vb1 = *(const f4*)(b1 + sb + q * 4);
#pragma unroll
        for (int j = 0; j < 4; j++) {
            a[q * 4 + j] = 1.f / (1.f + __expf(-(vg0[j] + vg1[j] + gb)));
            bb[q * 4 + j] = vb0[j] + vb1[j];
        }
    }
    float A = 1.f, Bv = 0.f;
#pragma unroll
    for (int i = 0; i < 16; i++) { Bv = a[i] * Bv + bb[i]; A *= a[i]; }
    SA[t] = A; SB[t] = Bv;
    __syncthreads();
    for (int off = 1; off < 256; off <<= 1) {
        float a1 = 1.f, b1v = 0.f;
        if (t >= off) { a1 = SA[t - off]; b1v = SB[t - off]; }
        float a2 = SA[t], b2 = SB[t];
        __syncthreads();
        SA[t] = a1 * a2;
        SB[t] = a2 * b1v + b2;
        __syncthreads();
    }
    float h = (t == 0) ? 0.f : SB[t - 1];
    float hv[16];
#pragma unroll
    for (int i = 0; i < 16; i++) {
        h = a[i] * h + bb[i];
        hv[i] = h;
    }
    ushort_t* dst = hT + (size_t)bn * 4096 + sb;
    u32x4 o0 = { cvtpk(hv[0], hv[1]),  cvtpk(hv[2], hv[3]),
                 cvtpk(hv[4], hv[5]),  cvtpk(hv[6], hv[7]) };
    u32x4 o1 = { cvtpk(hv[8], hv[9]),  cvtpk(hv[10], hv[11]),
                 cvtpk(hv[12], hv[13]), cvtpk(hv[14], hv[15]) };
    *(u32x4*)(dst)     = o0;
    *(u32x4*)(dst + 8) = o1;
}

// ---------------------------------------------------------------------------
// gemm_out256: out = (h@C_W) * sigmoid(x_hi @ outWt^T).
// FROZEN R11 (best known, ~56 us): 256x256 tile, 8 waves (2Mx4N), dbuf LDS,
// T2 XOR-swizzle, counted schedule with cross-phase A-quarter register
// prefetch (aR0/aR1, lgkmcnt(4)), vmcnt(2)@q0 / vmcnt(2)@q2, stages only into
// buf^1, conflict-free hT transpose (0 bank conflicts measured), XCD chunk map.
// ---------------------------------------------------------------------------
__global__ __launch_bounds__(512, 2)
void gemm_out256(const ushort_t* __restrict__ x_hi, const ushort_t* __restrict__ outWt,
                 const ushort_t* __restrict__ hT, const ushort_t* __restrict__ Ct,
                 float* __restrict__ out)
{
    __shared__ ushort_t As[2][256 * 64];   // 64 KiB
    __shared__ ushort_t Bs[2][256 * 64];   // 64 KiB

    const int tid = threadIdx.x;
    const int wave = tid >> 6, lane = tid & 63;
    const int wm = wave >> 2;          // 0..1
    const int wn = wave & 3;           // 0..3

    // XCD chunking: XCD k (= flat&7) owns m-tiles 8k..8k+7, sweeps n within.
    const int flat = blockIdx.x;
    const int swz = (flat & 7) * 32 + (flat >> 3);
    const int m0 = (swz >> 2) * 256;
    const int n0 = (swz & 3) * 256;

    const int lcol0 = (lane >> 4) * 8;
    const int lrow = lane & 15;
    const int lxor = (lrow & 7) << 3;

    // per-lane LDS read offsets (elements); quarter = +q*4096
    const int aOff0 = (wm * 32 + lrow) * 64 + (lcol0 ^ lxor);
    const int aOff1 = (wm * 32 + lrow) * 64 + ((32 + lcol0) ^ lxor);
    const int bOff0 = (wn * 64 + lrow) * 64 + (lcol0 ^ lxor);
    const int bOff1 = (wn * 64 + lrow) * 64 + ((32 + lcol0) ^ lxor);

    // persistent global stage streams (advance +64 elements per stage)
    const int rl0 = tid >> 3;                       // 0..63
    const int col0 = ((tid & 7) ^ (rl0 & 7)) << 3;  // inverse-swizzled source
    const ushort_t* gB0a = outWt + (size_t)(n0 + rl0) * 1024 + col0;
    const ushort_t* gB0b = gB0a + 64 * 1024;
    const ushort_t* gB1a = outWt + (size_t)(n0 + 128 + rl0) * 1024 + col0;
    const ushort_t* gB1b = gB1a + 64 * 1024;
    const ushort_t* gA0a = x_hi + (size_t)(m0 + rl0) * 1024 + col0;
    const ushort_t* gA0b = gA0a + 64 * 1024;
    const ushort_t* gA1a = x_hi + (size_t)(m0 + 128 + rl0) * 1024 + col0;
    const ushort_t* gA1b = gA1a + 64 * 1024;

    auto STG = [&](const ushort_t*& ga, const ushort_t*& gb, ushort_t* ldsbase) {
        gload_lds16(ga, ldsbase + wave * 512);
        gload_lds16(gb, ldsbase + 4096 + wave * 512);
        ga += 64; gb += 64;
    };

    f32x4 acc[8][4];
#pragma unroll
    for (int i = 0; i < 8; i++)
#pragma unroll
        for (int j = 0; j < 4; j++) { f32x4 z = {0.f,0.f,0.f,0.f}; acc[i][j] = z; }

    // prologue: stage tile 0; retire B0,B1,A0 (A1 stays in flight); read quarter0.
    STG(gB0a, gB0b, &Bs[0][0]);
    STG(gB1a, gB1b, &Bs[0][8192]);
    STG(gA0a, gA0b, &As[0][0]);
    STG(gA1a, gA1b, &As[0][8192]);
    asm volatile("s_waitcnt vmcnt(2)" ::: "memory");
    __builtin_amdgcn_s_barrier();

    short8 aR0[2][2], aR1[2][2], bfr[4][2];
#pragma unroll
    for (int mm = 0; mm < 2; ++mm) {
        aR0[mm][0] = *(const short8*)&As[0][aOff0 + mm * 1024];
        aR0[mm][1] = *(const short8*)&As[0][aOff1 + mm * 1024];
    }

#define MFMA_Q(q, AR)                                                              \
    do {                                                                           \
        __builtin_amdgcn_s_setprio(1);                                             \
        _Pragma("unroll") for (int mm = 0; mm < 2; ++mm)                           \
            _Pragma("unroll") for (int fn = 0; fn < 4; ++fn) {                     \
                acc[2*(q)+mm][fn] = __builtin_amdgcn_mfma_f32_16x16x32_bf16(       \
                    AR[mm][0], bfr[fn][0], acc[2*(q)+mm][fn], 0, 0, 0);            \
                acc[2*(q)+mm][fn] = __builtin_amdgcn_mfma_f32_16x16x32_bf16(       \
                    AR[mm][1], bfr[fn][1], acc[2*(q)+mm][fn], 0, 0, 0);            \
            }                                                                      \
        __builtin_amdgcn_s_setprio(0);                                             \
    } while (0)

    for (int t = 0; t < 16; ++t) {
        const int bc = t & 1;
        const ushort_t* as = &As[bc][0];
        const ushort_t* bs = &Bs[bc][0];
        const ushort_t* asn = &As[bc ^ 1][0];

        // ---- q0: MFMA quarter0 (aR0); read B(t) + quarter1 -> aR1 ----
        if (t < 15) STG(gB0a, gB0b, &Bs[bc ^ 1][0]);           // B0(t+1)
#pragma unroll
        for (int fn = 0; fn < 4; ++fn) {
            bfr[fn][0] = *(const short8*)(bs + bOff0 + fn * 1024);
            bfr[fn][1] = *(const short8*)(bs + bOff1 + fn * 1024);
        }
#pragma unroll
        for (int mm = 0; mm < 2; ++mm) {
            aR1[mm][0] = *(const short8*)(as + aOff0 + 4096 + mm * 1024);
            aR1[mm][1] = *(const short8*)(as + aOff1 + 4096 + mm * 1024);
        }
        asm volatile("s_waitcnt lgkmcnt(4)" ::: "memory");
        __builtin_amdgcn_sched_barrier(0);
        MFMA_Q(0, aR0);
        if (t < 15) { asm volatile("s_waitcnt vmcnt(2)" ::: "memory"); }  // retire A1(t)
        else        { asm volatile("s_waitcnt vmcnt(0)" ::: "memory"); }
        __builtin_amdgcn_s_barrier();

        // ---- q1: MFMA quarter1 (aR1); read quarter2 -> aR0 ----
        if (t < 15) {
            STG(gB1a, gB1b, &Bs[bc ^ 1][8192]);                // B1(t+1)
            STG(gA0a, gA0b, &As[bc ^ 1][0]);                   // A0(t+1)
        }
#pragma unroll
        for (int mm = 0; mm < 2; ++mm) {
            aR0[mm][0] = *(const short8*)(as + aOff0 + 2 * 4096 + mm * 1024);
            aR0[mm][1] = *(const short8*)(as + aOff1 + 2 * 4096 + mm * 1024);
        }
        asm volatile("s_waitcnt lgkmcnt(4)" ::: "memory");
        __builtin_amdgcn_sched_barrier(0);
        MFMA_Q(1, aR1);
        __builtin_amdgcn_s_barrier();

        // ---- q2: MFMA quarter2 (aR0); read quarter3 -> aR1 ----
        if (t < 15) STG(gA1a, gA1b, &As[bc ^ 1][8192]);        // A1(t+1)
#pragma unroll
        for (int mm = 0; mm < 2; ++mm) {
            aR1[mm][0] = *(const short8*)(as + aOff0 + 3 * 4096 + mm * 1024);
            aR1[mm][1] = *(const short8*)(as + aOff1 + 3 * 4096 + mm * 1024);
        }
        asm volatile("s_waitcnt lgkmcnt(4)" ::: "memory");
        __builtin_amdgcn_sched_barrier(0);
        MFMA_Q(2, aR0);
        if (t < 15) { asm volatile("s_waitcnt vmcnt(2)" ::: "memory"); }  // retire B0,B1,A0(t+1)
        __builtin_amdgcn_s_barrier();

        // ---- q3: MFMA quarter3 (aR1); read quarter0(t+1) -> aR0 ----
        if (t < 15) {
#pragma unroll
            for (int mm = 0; mm < 2; ++mm) {
                aR0[mm][0] = *(const short8*)(asn + aOff0 + mm * 1024);
                aR0[mm][1] = *(const short8*)(asn + aOff1 + mm * 1024);
            }
            asm volatile("s_waitcnt lgkmcnt(4)" ::: "memory");
        } else {
            asm volatile("s_waitcnt lgkmcnt(0)" ::: "memory");
        }
        __builtin_amdgcn_sched_barrier(0);
        MFMA_Q(3, aR1);
        __builtin_amdgcn_s_barrier();
    }
#undef MFMA_Q

    // ---------- fused y epilogue: y = h @ C_W on this tile (K = 64) ----------
    const int b64 = (m0 >> 12) * 64;
    const int sb0 = m0 & 4095;
    // Bs[0] <- Ct rows n0..n0+255 (gload_lds, pre-swizzled source)
#pragma unroll
    for (int p = 0; p < 4; ++p) {
        int c = p * 512 + wave * 64 + lane;
        int row = c >> 3;
        int col = (((c & 7) ^ (row & 7)) << 3);
        gload_lds16(Ct + (size_t)(n0 + row) * 64 + col,
                    &Bs[0][(p * 512 + wave * 64) * 8]);
    }
    // As[0] <- transpose(hT). Conflict-free: kn = c&63 per-lane consecutive,
    // mc = c>>6 wave-uniform -> 64 lanes write one row, 2 lanes/bank = free.
#pragma unroll
    for (int p = 0; p < 4; ++p) {
        int c = tid + p * 512;           // kn = c&63, mc = c>>6 (0..31)
        int kn = c & 63, mc = c >> 6;
        short8 v = *(const short8*)(hT + (size_t)(b64 + kn) * 4096 + sb0 + mc * 8);
#pragma unroll
        for (int j = 0; j < 8; ++j)
            As[0][SWIDX(mc * 8 + j, kn)] = (ushort_t)v[j];
    }
    __syncthreads();

    short8 by[4][2];
#pragma unroll
    for (int fn = 0; fn < 4; fn++)
#pragma unroll
        for (int kk = 0; kk < 2; kk++) {
            int r = wn * 64 + fn * 16 + lrow;
            by[fn][kk] = *(const short8*)&Bs[0][SWIDX(r, kk * 32 + lcol0)];
        }

#pragma unroll
    for (int g = 0; g < 4; g++) {        // register-sliced: 2 m-frags at a time
        f32x4 ty[2][4];
#pragma unroll
        for (int mm = 0; mm < 2; mm++)
#pragma unroll
            for (int fn = 0; fn < 4; fn++) { f32x4 z = {0.f,0.f,0.f,0.f}; ty[mm][fn] = z; }
#pragma unroll
        for (int mm = 0; mm < 2; mm++) {
            int r = g * 64 + wm * 32 + mm * 16 + lrow;
            short8 a0 = *(const short8*)&As[0][SWIDX(r, lcol0)];
            short8 a1 = *(const short8*)&As[0][SWIDX(r, 32 + lcol0)];
#pragma unroll
            for (int fn = 0; fn < 4; fn++) {
                ty[mm][fn] = __builtin_amdgcn_mfma_f32_16x16x32_bf16(a0, by[fn][0], ty[mm][fn], 0, 0, 0);
                ty[mm][fn] = __builtin_amdgcn_mfma_f32_16x16x32_bf16(a1, by[fn][1], ty[mm][fn], 0, 0, 0);
            }
        }
#pragma unroll
        for (int mm = 0; mm < 2; mm++)
#pragma unroll
            for (int fn = 0; fn < 4; fn++) {
                int col = n0 + wn * 64 + fn * 16 + lrow;
                int rbase = m0 + g * 64 + wm * 32 + mm * 16 + ((lane >> 4) << 2);
#pragma unroll
                for (int r = 0; r < 4; r++) {
                    float og = 1.f / (1.f + __expf(-acc[g * 2 + mm][fn][r]));
                    out[(size_t)(rbase + r) * 1024 + col] = ty[mm][fn][r] * og;
                }
            }
    }
}

// ---------------------------------------------------------------------------
extern "C" void kernel_launch(void* const* d_in, const int* in_sizes, int n_in,
                              void* d_out, int out_size, void* d_ws, size_t ws_size,
                              hipStream_t stream)
{
    const float* x      = (const float*)d_in[0];   // (4,4096,1024)
    const float* gate_W = (const float*)d_in[1];   // (1024,64)
    const float* gate_b = (const float*)d_in[2];   // (64,)
    const float* B_W    = (const float*)d_in[3];   // (1024,64)
    const float* C_W    = (const float*)d_in[4];   // (64,1024)
    const float* out_W  = (const float*)d_in[5];   // (1024,1024)
    // d_in[6] mix_weight cancels (h_next == h_final); d_in[7] chunk_size unused.
    float* out = (float*)d_out;

    char* ws = (char*)d_ws;
    float*    Zpart  = (float*)(ws + 0);            // 16 MiB [2][512][4096] fp32
    ushort_t* hT     = (ushort_t*)(ws + 16777216);  //  2 MiB [256][4096]
    ushort_t* x_hi   = (ushort_t*)(ws + 18874368);  // 32 MiB [16384][1024]
    ushort_t* W1t_hi = (ushort_t*)(ws + 52428800);  // [128][1024]
    ushort_t* W1t_lo = (ushort_t*)(ws + 52690944);
    ushort_t* outWt  = (ushort_t*)(ws + 52953088);  // [1024][1024]
    ushort_t* Ct     = (ushort_t*)(ws + 55050240);  // [1024][64]

    prep_weights<<<512, 256, 0, stream>>>(gate_W, B_W, C_W, out_W,
                                          W1t_hi, W1t_lo, outWt, Ct);

    p1_kernel<<<dim3(256, 2), 256, 0, stream>>>(x, W1t_hi, W1t_lo, x_hi, Zpart);

    scan_kernel<<<256, 256, 0, stream>>>(Zpart, gate_b, hT);

    gemm_out256<<<256, 512, 0, stream>>>(x_hi, outWt, hT, Ct, out);
}